// Round 1
// baseline (448.204 us; speedup 1.0000x reference)
//
#include <hip/hip_runtime.h>
#include <hip/hip_bf16.h>

#define BB 32
#define LL 128
#define DD 400
#define KK 40
#define EE 416   // e padded to 13*32
#define SDN 50   // d-slot count (400/8)
#define SEN 52   // e-slot count (416/8)

typedef __attribute__((ext_vector_type(8)))  short  bfrag;   // 8 bf16 = 4 VGPRs
typedef __attribute__((ext_vector_type(16))) float  ffrag;   // 16 fp32 acc

static __device__ __forceinline__ short f2bf(float f) {
    union { float f; unsigned u; } v; v.f = f;
    unsigned r = (v.u + 0x7FFF + ((v.u >> 16) & 1)) >> 16;
    return (short)r;
}

#define MFMA32(a, b, c) __builtin_amdgcn_mfma_f32_32x32x16_bf16((a), (b), (c), 0, 0, 0)

// ---------------------------------------------------------------------------
// Prep: Hslots[b][sd][h][8] = bf16(H[b][h][8sd..8sd+7])
//       Cslots[b][se][c][8] = bf16(C[b][c][8se..]) with zero pad e>=400
// ---------------------------------------------------------------------------
__global__ __launch_bounds__(256) void p_hc(
    const float* __restrict__ H, const float* __restrict__ C,
    short* __restrict__ Hs, short* __restrict__ Cs)
{
    int id = blockIdx.x * 256 + threadIdx.x;
    if (id < BB*SDN*LL) {
        int b = id / (SDN*LL); int r = id % (SDN*LL);
        int sd = r / LL; int h = r % LL;
        const float* src = H + ((size_t)(b*LL + h))*DD + sd*8;
        bfrag v;
#pragma unroll
        for (int j = 0; j < 8; ++j) v[j] = f2bf(src[j]);
        *(bfrag*)(Hs + (size_t)id*8) = v;
    } else {
        id -= BB*SDN*LL;
        int b = id / (SEN*LL); int r = id % (SEN*LL);
        int se = r / LL; int c = r % LL;
        bfrag v;
#pragma unroll
        for (int j = 0; j < 8; ++j) {
            int e = se*8 + j;
            v[j] = (e < DD) ? f2bf(C[((size_t)(b*LL + c))*DD + e]) : (short)0;
        }
        *(bfrag*)(Cs + (size_t)id*8) = v;
    }
}

// Uslots[k][sd][e][8] = bf16(U[k][8sd+j][e]), zeros for e >= 400
__global__ __launch_bounds__(256) void p_u(
    const float* __restrict__ U, short* __restrict__ Us)
{
    int id = blockIdx.x * 256 + threadIdx.x;   // < 40*50*416
    int k = id / (SDN*EE); int r = id % (SDN*EE);
    int sd = r / EE; int e = r % EE;
    bfrag v;
#pragma unroll
    for (int j = 0; j < 8; ++j)
        v[j] = (e < DD) ? f2bf(U[((size_t)k*DD + sd*8 + j)*DD + e]) : (short)0;
    *(bfrag*)(Us + (size_t)id*8) = v;
}

// ---------------------------------------------------------------------------
// SD[b,k,h] = W_d[k].h[b,h]   SE[b,k,c] = W_e[k].c[b,c]   (fp32 exact)
// Rewritten: one pass over H/C (was 40x re-read = 524 MB of L2/L3 traffic).
// grid (b, src, rowgroup); thread = (row, d-quarter); 40 k accumulators in
// registers, quarter-sums combined with shfl_xor across 4 lanes.
// ---------------------------------------------------------------------------
__global__ __launch_bounds__(256) void k_sdse(
    const float* __restrict__ H, const float* __restrict__ C,
    const float* __restrict__ Wd, const float* __restrict__ We,
    float* __restrict__ SD, float* __restrict__ SE)
{
    const int b   = blockIdx.x;
    const int src = blockIdx.y;      // 0 = H->SD, 1 = C->SE
    const int rg  = blockIdx.z;      // 0/1: rows 0..63 / 64..127
    const int t = threadIdx.x;
    const int row = rg*64 + (t >> 2);
    const int q = t & 3;             // d-quarter: 100 d's each
    const float* __restrict__ X = (src == 0 ? H : C) + ((size_t)(b*LL + row))*DD + q*100;
    const float* __restrict__ W = (src == 0 ? Wd : We) + q*100;
    float acc[KK];
#pragma unroll
    for (int k = 0; k < KK; ++k) acc[k] = 0.f;
    for (int dc = 0; dc < 25; ++dc) {
        float4 v = *(const float4*)(X + 4*dc);
#pragma unroll
        for (int k = 0; k < KK; ++k) {
            float4 wv = *(const float4*)(W + (size_t)k*DD + 4*dc);
            acc[k] = fmaf(v.x, wv.x, acc[k]);
            acc[k] = fmaf(v.y, wv.y, acc[k]);
            acc[k] = fmaf(v.z, wv.z, acc[k]);
            acc[k] = fmaf(v.w, wv.w, acc[k]);
        }
    }
#pragma unroll
    for (int k = 0; k < KK; ++k) {
        acc[k] += __shfl_xor(acc[k], 1);
        acc[k] += __shfl_xor(acc[k], 2);
    }
    if (q == 0) {
        float* out = (src == 0 ? SD : SE) + ((size_t)b*KK)*LL + row;
#pragma unroll
        for (int k = 0; k < KK; ++k) out[k*LL] = acc[k];
    }
}

// ---------------------------------------------------------------------------
// Main MFMA kernel, restructured:
//   grid (8 k-groups, 32 b), 512 threads = 8 waves.
//   Block (g,b) loops k = g + 8*kk (kk=0..4) — the 5 k's of slice g — and
//   accumulates exp(energy) in registers (Eacc). Slice written once,
//   NON-atomically (was 21M global atomicAdds). blockIdx.x = g also pins
//   each k-group to one XCD (linear%8) so the Us slice is L2-resident.
//   Phase 1: T[e,h] = sum_d U[k,d,e] H[b,h,d]; 3-deep SW pipeline.
//   Phase 2: S[h,c] += sum_e T[e,h] C[b,c,e]; 2-deep SW pipeline.
//   Per-wave roles: phase1 (et = w>>1 e-subtile, hh = w&1 h-half);
//                   phase2 (ht = w>>1 h-tile,   ch = w&1 c-half).
// ---------------------------------------------------------------------------
__global__ __launch_bounds__(512, 2) void k_mfma(
    const short* __restrict__ Hs, const short* __restrict__ Cs,
    const short* __restrict__ Us,
    const float* __restrict__ SD, const float* __restrict__ SE,
    const float* __restrict__ bvec, const float* __restrict__ mask,
    const int* __restrict__ heads, const int* __restrict__ tags,
    float* __restrict__ A8, float* __restrict__ tgt)
{
    const int g = blockIdx.x;      // k-group / slice / XCD
    const int b = blockIdx.y;
    const int t = threadIdx.x;
    const int w  = t >> 6;         // 0..7
    const int l  = t & 63;
    const int l31 = l & 31;
    const int kh  = l >> 5;        // 0/1 (K-half of MFMA operands)
    const int et = w >> 1;         // phase1: e-subtile (32) within 128-chunk
    const int hh = w & 1;          // phase1: h-half
    const int ht = w >> 1;         // phase2: h-tile (32)
    const int ch = w & 1;          // phase2: c-half

    __shared__ short Tbuf[16*LL*8];   // [s_e(16)][h(128)][8]  32 KB

    const size_t hsB = (size_t)b * SDN * LL;
    const size_t csB = (size_t)b * SEN * LL;

    // ---- per-thread epilogue constants (k-invariant, hoisted) ----
    const int hbase = 32*ht + 4*kh;          // + (r&3)+8*(r>>2) gives row h
    const int c0 = 64*ch + l31;
    const int c1 = c0 + 32;
    const float mc0 = mask[b*LL + c0], mc1 = mask[b*LL + c1];
    const int head0 = heads[b*LL + c0], head1 = heads[b*LL + c1];
    const int tag0  = tags[b*LL + c0],  tag1  = tags[b*LL + c1];
    unsigned vb0 = 0, vb1 = 0;
#pragma unroll
    for (int r = 0; r < 16; ++r) {
        const int hr = hbase + (r&3) + 8*(r>>2);
        const float mh = mask[b*LL + hr];
        if (mh != 0.f && mc0 != 0.f && hr != c0) vb0 |= 1u << r;
        if (mh != 0.f && mc1 != 0.f && hr != c1) vb1 |= 1u << r;
    }

    ffrag E0, E1, S0, S1;
#pragma unroll
    for (int r = 0; r < 16; ++r) { E0[r] = 0.f; E1[r] = 0.f; }

    for (int kk = 0; kk < 5; ++kk) {
        const int k = g + 8*kk;
        const size_t usK = (size_t)k * SDN * EE;
#pragma unroll
        for (int r = 0; r < 16; ++r) { S0[r] = 0.f; S1[r] = 0.f; }

        for (int chunk = 0; chunk < 4; ++chunk) {
            const int e0 = chunk << 7;
            const bool tail = (chunk == 3);     // only e 384..415 valid

            // ---- Phase 1: T[e_chunk, h] over all d ----
            if (!tail || et == 0) {
                ffrag T0, T1;
#pragma unroll
                for (int r = 0; r < 16; ++r) { T0[r] = 0.f; T1[r] = 0.f; }
                const short* up  = Us + (usK + (size_t)(e0 + 32*et + l31) + (size_t)kh*EE)*8;
                const short* hp0 = Hs + (hsB + (size_t)(64*hh + l31) + (size_t)kh*LL)*8;
                const short* hp1 = hp0 + 32*8;
#define UF(i) (*(const bfrag*)(up  + (size_t)(i)*(2*EE*8)))
#define XF(i) (*(const bfrag*)(hp0 + (size_t)(i)*(2*LL*8)))
#define YF(i) (*(const bfrag*)(hp1 + (size_t)(i)*(2*LL*8)))
                // 25 K-steps (K=16 each): 3-deep software pipeline
                bfrag a0=UF(0), x0=XF(0), y0=YF(0);
                bfrag a1=UF(1), x1=XF(1), y1=YF(1);
                bfrag a2=UF(2), x2=XF(2), y2=YF(2);
#pragma unroll 1
                for (int j = 0; j < 8; ++j) {
                    const int i0 = (3*j+3 < 25) ? 3*j+3 : 24;   // clamp: dup of 24,
                    const int i1 = (3*j+4 < 25) ? 3*j+4 : 24;   // never consumed
                    const int i2 = (3*j+5 < 25) ? 3*j+5 : 24;
                    bfrag a3=UF(i0), x3=XF(i0), y3=YF(i0);
                    bfrag a4=UF(i1), x4=XF(i1), y4=YF(i1);
                    bfrag a5=UF(i2), x5=XF(i2), y5=YF(i2);
                    T0 = MFMA32(a0, x0, T0); T1 = MFMA32(a0, y0, T1);
                    T0 = MFMA32(a1, x1, T0); T1 = MFMA32(a1, y1, T1);
                    T0 = MFMA32(a2, x2, T0); T1 = MFMA32(a2, y2, T1);
                    a0=a3; x0=x3; y0=y3; a1=a4; x1=x4; y1=y4; a2=a5; x2=x5; y2=y5;
                }
                T0 = MFMA32(a0, x0, T0); T1 = MFMA32(a0, y0, T1);   // step 24
#undef UF
#undef XF
#undef YF
                // write T tiles to LDS in phase-2 A-fragment layout
                const int hA = 64*hh + l31;
#pragma unroll
                for (int r = 0; r < 16; r += 2) {
                    const int e_loc = 32*et + (r&3) + 8*(r>>2) + 4*kh;
                    const int s_e = e_loc >> 3, e7 = e_loc & 7;
                    unsigned lo0 = (unsigned short)f2bf(T0[r]);
                    unsigned hi0 = (unsigned short)f2bf(T0[r+1]);
                    *(unsigned*)(&Tbuf[((size_t)s_e*LL + hA)*8 + e7]) = lo0 | (hi0 << 16);
                    unsigned lo1 = (unsigned short)f2bf(T1[r]);
                    unsigned hi1 = (unsigned short)f2bf(T1[r+1]);
                    *(unsigned*)(&Tbuf[((size_t)s_e*LL + hA + 32)*8 + e7]) = lo1 | (hi1 << 16);
                }
            }
            __syncthreads();

            // ---- Phase 2: S[h,c] += T[e_chunk,h]^T-style MFMA with C ----
            const short* tb  = Tbuf + ((size_t)(kh*LL) + 32*ht + l31)*8;
            const short* cp0 = Cs + (csB + (size_t)((chunk*16 + kh)*LL) + 64*ch + l31)*8;
            const short* cp1 = cp0 + 32*8;
#define TF(es) (*(const bfrag*)(tb  + (size_t)(es)*(2*LL*8)))
#define PF(es) (*(const bfrag*)(cp0 + (size_t)(es)*(2*LL*8)))
#define QF(es) (*(const bfrag*)(cp1 + (size_t)(es)*(2*LL*8)))
            if (!tail) {
                // 8 K-steps: 2-deep pipeline (pairs)
                bfrag t0=TF(0), u0=PF(0), v0=QF(0);
                bfrag t1=TF(1), u1=PF(1), v1=QF(1);
#pragma unroll 1
                for (int it = 0; it < 3; ++it) {
                    bfrag t2=TF(2*it+2), u2=PF(2*it+2), v2=QF(2*it+2);
                    bfrag t3=TF(2*it+3), u3=PF(2*it+3), v3=QF(2*it+3);
                    S0 = MFMA32(t0, u0, S0); S1 = MFMA32(t0, v0, S1);
                    S0 = MFMA32(t1, u1, S0); S1 = MFMA32(t1, v1, S1);
                    t0=t2; u0=u2; v0=v2; t1=t3; u1=u3; v1=v3;
                }
                S0 = MFMA32(t0, u0, S0); S1 = MFMA32(t0, v0, S1);
                S0 = MFMA32(t1, u1, S0); S1 = MFMA32(t1, v1, S1);
            } else {
                bfrag t0=TF(0), u0=PF(0), v0=QF(0);
                bfrag t1=TF(1), u1=PF(1), v1=QF(1);
                S0 = MFMA32(t0, u0, S0); S1 = MFMA32(t0, v0, S1);
                S0 = MFMA32(t1, u1, S0); S1 = MFMA32(t1, v1, S1);
            }
#undef TF
#undef PF
#undef QF
            __syncthreads();   // Tbuf reused next chunk / next k
        }

        // ---- per-k epilogue: accumulate exp(energy) into E, tgt ----
        const float bk = bvec[k];
        const float* SDb = SD + ((size_t)b*KK + k)*LL;
        const float* SEb = SE + ((size_t)b*KK + k)*LL;
        const float se0 = SEb[c0], se1 = SEb[c1];
#pragma unroll
        for (int r = 0; r < 16; ++r) {
            const int hr = hbase + (r&3) + 8*(r>>2);
            const float sdv = SDb[hr];
            const float e0v = S0[r] + sdv + se0 + bk;
            const float e1v = S1[r] + sdv + se1 + bk;
            if ((vb0 >> r) & 1) E0[r] += __expf(e0v);
            if ((vb1 >> r) & 1) E1[r] += __expf(e1v);
            if (((vb0 >> r) & 1) && c0 >= 1 && tag0 == k && head0 == hr)
                atomicAdd(&tgt[b], e0v);
            if (((vb1 >> r) & 1) && c1 >= 1 && tag1 == k && head1 == hr)
                atomicAdd(&tgt[b], e1v);
        }
    }

    // ---- write slice g (exclusive ownership: no atomics, no memset) ----
    float* Ab = A8 + ((size_t)(g*BB + b))*LL*LL;
#pragma unroll
    for (int r = 0; r < 16; ++r) {
        const int hr = hbase + (r&3) + 8*(r>>2);
        Ab[hr*LL + c0] = E0[r];
        Ab[hr*LL + c1] = E1[r];
    }
}

// ---------------------------------------------------------------------------
// Register-resident LU logdet (unchanged).
// ---------------------------------------------------------------------------
__global__ __launch_bounds__(256) void k_logdet(
    const float* __restrict__ A8, const int* __restrict__ lengths,
    const float* __restrict__ tgt, float* __restrict__ out)
{
    const int b = blockIdx.x;
    const int t = threadIdx.x;
    const int rg = t >> 4;      // 0..15 row-group
    const int cg = t & 15;      // 0..15 col-group

    __shared__ float As[LL*LL];     // 64 KB
    __shared__ float Dg[128];       // col sums, then pivot stash
    __shared__ float Lbuf[128];
    __shared__ float Ubuf[128];
    __shared__ float red[256];

    const float4* A4 = (const float4*)A8;
    for (int f4 = t; f4 < 4096; f4 += 256) {
        float4 s = make_float4(0.f, 0.f, 0.f, 0.f);
#pragma unroll
        for (int g = 0; g < 8; ++g) {
            float4 v = A4[((size_t)(g*BB + b))*4096 + f4];
            s.x += v.x; s.y += v.y; s.z += v.z; s.w += v.w;
        }
        ((float4*)As)[f4] = s;
    }
    __syncthreads();

    if (t < 128) {
        float s = 0.f;
        for (int hr = 0; hr < LL; ++hr) s += As[hr*LL + t];
        Dg[t] = s * (1.0f + 1e-4f) + 1e-6f;
    }
    __syncthreads();

    const int n1 = lengths[b] - 1;
    float m[8][8];
#pragma unroll
    for (int r = 0; r < 8; ++r) {
        const int i = 8*rg + r;
#pragma unroll
        for (int c = 0; c < 8; ++c) {
            const int j = 8*cg + c;
            float v;
            if (i < n1 && j < n1)
                v = ((i == j) ? Dg[i+1] : 0.f) - As[(i+1)*LL + (j+1)];
            else
                v = (i == j) ? 1.f : 0.f;
            m[r][c] = v;
        }
    }
    __syncthreads();

    for (int j = 0; j < 127; ++j) {
        const int jg = j >> 3, jl = j & 7;
        if (cg == jg) {
#pragma unroll
            for (int c = 0; c < 8; ++c) {
                if (c == jl) {
#pragma unroll
                    for (int r = 0; r < 8; ++r) Lbuf[8*rg + r] = m[r][c];
                }
            }
        }
        if (rg == jg) {
#pragma unroll
            for (int r = 0; r < 8; ++r) {
                if (r == jl) {
#pragma unroll
                    for (int c = 0; c < 8; ++c) Ubuf[8*cg + c] = m[r][c];
                }
            }
        }
        __syncthreads();

        const float piv = Lbuf[j];
        if (t == j) Dg[j] = piv;
        const float rp = 1.0f / piv;
        float lr[8], ur[8];
#pragma unroll
        for (int r = 0; r < 8; ++r) lr[r] = Lbuf[8*rg + r] * rp;
#pragma unroll
        for (int c = 0; c < 8; ++c) ur[c] = Ubuf[8*cg + c];
#pragma unroll
        for (int r = 0; r < 8; ++r)
#pragma unroll
            for (int c = 0; c < 8; ++c)
                m[r][c] = fmaf(-lr[r], ur[c], m[r][c]);
        __syncthreads();
    }

    float lsum = 0.f;
    if (t < 127) lsum = logf(Dg[t]);
    red[t] = lsum;
    __syncthreads();
    for (int off = 128; off >= 1; off >>= 1) {
        if (t < off) red[t] += red[t + off];
        __syncthreads();
    }
    if (t == 0) out[b] = red[0] - tgt[b];
}

// ---------------------------------------------------------------------------
extern "C" void kernel_launch(void* const* d_in, const int* in_sizes, int n_in,
                              void* d_out, int out_size, void* d_ws, size_t ws_size,
                              hipStream_t stream) {
    const float* H    = (const float*)d_in[0];
    const float* C    = (const float*)d_in[1];
    const float* Wd   = (const float*)d_in[2];
    const float* We   = (const float*)d_in[3];
    const float* U    = (const float*)d_in[4];
    const float* bv   = (const float*)d_in[5];
    const float* mask = (const float*)d_in[6];
    const int* heads  = (const int*)d_in[7];
    const int* tags   = (const int*)d_in[8];
    const int* lens   = (const int*)d_in[9];
    float* out = (float*)d_out;

    // workspace layout
    char* p = (char*)d_ws;
    float* A8  = (float*)p;                 p += (size_t)8*BB*LL*LL*4;      // 16.78 MB
    float* tgt = (float*)p;                 p += 32*4;
    float* SDp = (float*)p;                 p += (size_t)BB*KK*LL*4;
    float* SEp = (float*)p;                 p += (size_t)BB*KK*LL*4;
    short* Hsp = (short*)p;                 p += (size_t)BB*SDN*LL*8*2;
    short* Csp = (short*)p;                 p += (size_t)BB*SEN*LL*8*2;
    short* Usp = (short*)p;                 p += (size_t)KK*SDN*EE*8*2;

    // only tgt needs zeroing now (A8 slices are fully overwritten)
    hipMemsetAsync(tgt, 0, 32*4, stream);

    p_hc  <<<dim3(1632), 256, 0, stream>>>(H, C, Hsp, Csp);
    p_u   <<<dim3(3250), 256, 0, stream>>>(U, Usp);
    k_sdse<<<dim3(BB, 2, 2), 256, 0, stream>>>(H, C, Wd, We, SDp, SEp);
    k_mfma<<<dim3(8, BB), 512, 0, stream>>>(Hsp, Csp, Usp, SDp, SEp, bv, mask,
                                            heads, tags, A8, tgt);
    k_logdet<<<dim3(BB), 256, 0, stream>>>(A8, lens, tgt, out);
}

// Round 2
// 335.605 us; speedup vs baseline: 1.3355x; 1.3355x over previous
//
#include <hip/hip_runtime.h>
#include <hip/hip_bf16.h>

#define BB 32
#define LL 128
#define DD 400
#define KK 40
#define EE 416   // e padded to 13*32
#define SDN 50   // d-slot count (400/8)
#define SEN 52   // e-slot count (416/8)

typedef __attribute__((ext_vector_type(8)))  short  bfrag;   // 8 bf16 = 4 VGPRs
typedef __attribute__((ext_vector_type(16))) float  ffrag;   // 16 fp32 acc

static __device__ __forceinline__ short f2bf(float f) {
    union { float f; unsigned u; } v; v.f = f;
    unsigned r = (v.u + 0x7FFF + ((v.u >> 16) & 1)) >> 16;
    return (short)r;
}

#define MFMA32(a, b, c) __builtin_amdgcn_mfma_f32_32x32x16_bf16((a), (b), (c), 0, 0, 0)

// ---------------------------------------------------------------------------
// Prep: Hslots[b][sd][h][8] = bf16(H[b][h][8sd..8sd+7])
//       Cslots[b][se][c][8] = bf16(C[b][c][8se..]) with zero pad e>=400
// ---------------------------------------------------------------------------
__global__ __launch_bounds__(256) void p_hc(
    const float* __restrict__ H, const float* __restrict__ C,
    short* __restrict__ Hs, short* __restrict__ Cs)
{
    int id = blockIdx.x * 256 + threadIdx.x;
    if (id < BB*SDN*LL) {
        int b = id / (SDN*LL); int r = id % (SDN*LL);
        int sd = r / LL; int h = r % LL;
        const float* src = H + ((size_t)(b*LL + h))*DD + sd*8;
        bfrag v;
#pragma unroll
        for (int j = 0; j < 8; ++j) v[j] = f2bf(src[j]);
        *(bfrag*)(Hs + (size_t)id*8) = v;
    } else {
        id -= BB*SDN*LL;
        int b = id / (SEN*LL); int r = id % (SEN*LL);
        int se = r / LL; int c = r % LL;
        bfrag v;
#pragma unroll
        for (int j = 0; j < 8; ++j) {
            int e = se*8 + j;
            v[j] = (e < DD) ? f2bf(C[((size_t)(b*LL + c))*DD + e]) : (short)0;
        }
        *(bfrag*)(Cs + (size_t)id*8) = v;
    }
}

// Uslots[k][sd][e][8] = bf16(U[k][8sd+j][e]), zeros for e >= 400
__global__ __launch_bounds__(256) void p_u(
    const float* __restrict__ U, short* __restrict__ Us)
{
    int id = blockIdx.x * 256 + threadIdx.x;   // < 40*50*416
    int k = id / (SDN*EE); int r = id % (SDN*EE);
    int sd = r / EE; int e = r % EE;
    bfrag v;
#pragma unroll
    for (int j = 0; j < 8; ++j)
        v[j] = (e < DD) ? f2bf(U[((size_t)k*DD + sd*8 + j)*DD + e]) : (short)0;
    *(bfrag*)(Us + (size_t)id*8) = v;
}

// ---------------------------------------------------------------------------
// SD[b,k,h] = W_d[k].h[b,h]   SE[b,k,c] = W_e[k].c[b,c]   (fp32 exact)
// grid (32 b, 4 rowgroups, 2 src) = 256 blocks, 2/CU (64 KB LDS each).
// Per block: stage one W (40x400 fp32) in LDS; 32 rows x 8 lanes/row.
// Thread keeps its 50-float row slice in registers, loops all 40 k with
// LDS-broadcast W reads (conflict-free), 8-lane shfl reduce.
// ---------------------------------------------------------------------------
__global__ __launch_bounds__(256) void k_sdse(
    const float* __restrict__ H, const float* __restrict__ C,
    const float* __restrict__ Wd, const float* __restrict__ We,
    float* __restrict__ SD, float* __restrict__ SE)
{
    const int b   = blockIdx.x;
    const int rg  = blockIdx.y;      // 0..3 : rows rg*32 .. rg*32+31
    const int srcC = blockIdx.z;     // 0 = H->SD, 1 = C->SE
    const int t = threadIdx.x;

    __shared__ float Wl[KK*DD];      // 64 KB
    {
        const float4* Wsrc = (const float4*)(srcC ? We : Wd);
        for (int i = t; i < KK*DD/4; i += 256) ((float4*)Wl)[i] = Wsrc[i];
    }
    __syncthreads();

    const int task = t >> 3;         // 0..31 row within group
    const int p    = t & 7;          // d-octant: 50 floats each
    const int row  = rg*32 + task;
    const float* X = (srcC ? C : H) + ((size_t)(b*LL + row))*DD + p*50;

    float2 x[25];
#pragma unroll
    for (int i = 0; i < 25; ++i) x[i] = ((const float2*)X)[i];

    float* out = (srcC ? SE : SD) + (size_t)b*KK*LL + row;
    const float* Wb = Wl + p*50;

    for (int k = 0; k < KK; ++k) {
        const float2* wp = (const float2*)(Wb + k*DD);
        float s0 = 0.f, s1 = 0.f;
#pragma unroll
        for (int i = 0; i < 24; i += 2) {
            float2 w0 = wp[i], w1 = wp[i+1];
            s0 = fmaf(x[i].x,   w0.x, s0); s0 = fmaf(x[i].y,   w0.y, s0);
            s1 = fmaf(x[i+1].x, w1.x, s1); s1 = fmaf(x[i+1].y, w1.y, s1);
        }
        { float2 w0 = wp[24]; s0 = fmaf(x[24].x, w0.x, s0); s0 = fmaf(x[24].y, w0.y, s0); }
        float s = s0 + s1;
        s += __shfl_xor(s, 1); s += __shfl_xor(s, 2); s += __shfl_xor(s, 4);
        if (p == 0) out[k*LL] = s;
    }
}

// ---------------------------------------------------------------------------
// Main MFMA kernel:
//   grid (8 g, 32 b, 2 hh) = 512 blocks, 512 thr, 2 blocks/CU.
//   Block computes S[h in 64*hh..+63][c 0..127] for k = g+8*kk, kk=0..4;
//   exp accumulated in registers, slice-half written once, non-atomic.
//   Phase 1: T[e 0..415][64 h] = sum_d U.H  -> LDS (53 KB), e zero-padded
//            so no tail logic anywhere. 26 tiles / 8 waves (3-4 each).
//   Phase 2: each wave one 32x32 S-tile, 26 K-steps over e.
//   2 barriers per k (was 8).
// ---------------------------------------------------------------------------
__global__ __launch_bounds__(512, 4) void k_mfma(
    const short* __restrict__ Hs, const short* __restrict__ Cs,
    const short* __restrict__ Us,
    const float* __restrict__ SD, const float* __restrict__ SE,
    const float* __restrict__ bvec, const float* __restrict__ mask,
    const int* __restrict__ heads, const int* __restrict__ tags,
    float* __restrict__ A8, float* __restrict__ tgt)
{
    const int g  = blockIdx.x;     // k-group (also XCD via linear%8)
    const int b  = blockIdx.y;
    const int hh = blockIdx.z;     // h-half
    const int t  = threadIdx.x;
    const int w  = t >> 6;         // 0..7
    const int l31 = t & 31;
    const int kh  = (t >> 5) & 1;  // K-half of MFMA operands

    __shared__ short Tbuf[52*64*8];   // [s_e(52)][hl(64)][8]  53,248 B

    const size_t hsB = (size_t)b * SDN * LL;
    const size_t csB = (size_t)b * SEN * LL;

    // ---- phase-2 roles & k-invariant epilogue constants ----
    const int ht = w >> 2;            // h-tile (0..1)
    const int ct = w & 3;             // c-tile (0..3)
    const int hbase = 64*hh + 32*ht + 4*kh;
    const int c0 = 32*ct + l31;
    const float mc0 = mask[b*LL + c0];
    const int head0 = heads[b*LL + c0];
    const int tag0  = tags[b*LL + c0];
    unsigned vb = 0;
#pragma unroll
    for (int r = 0; r < 16; ++r) {
        const int hr = hbase + (r&3) + 8*(r>>2);
        if (mask[b*LL + hr] != 0.f && mc0 != 0.f && hr != c0) vb |= 1u << r;
    }

    ffrag E;
#pragma unroll
    for (int r = 0; r < 16; ++r) E[r] = 0.f;

    const int ntiles = (w < 2) ? 4 : 3;   // 26 T-tiles over 8 waves

    for (int kk = 0; kk < 5; ++kk) {
        const int k = g + 8*kk;
        const size_t usK = (size_t)k * SDN * EE;

        // ---- Phase 1: T[e, hl] for this h-half, all 416 e ----
        for (int ti = 0; ti < ntiles; ++ti) {
            const int tau = w + 8*ti;      // 0..25
            const int te = tau >> 1;       // e-tile 0..12
            const int th = tau & 1;        // h-subtile 0..1
            const short* up = Us + (usK + (size_t)kh*EE + 32*te + l31)*8;
            const short* hp = Hs + (hsB + (size_t)kh*LL + 64*hh + 32*th + l31)*8;
#define UP(i) (*(const bfrag*)(up + (size_t)(i)*(2*EE*8)))
#define HP(i) (*(const bfrag*)(hp + (size_t)(i)*(2*LL*8)))
            ffrag T;
#pragma unroll
            for (int r = 0; r < 16; ++r) T[r] = 0.f;
            // 25 K-steps, 2-deep pipeline; step 24 prefetched in prologue
            bfrag aA=UP(0), bA=HP(0), aB=UP(1), bB=HP(1);
            bfrag aL=UP(24), bL=HP(24);
#pragma unroll 1
            for (int j = 0; j < 11; ++j) {
                bfrag aC=UP(2*j+2), bC=HP(2*j+2);
                bfrag aD=UP(2*j+3), bD=HP(2*j+3);
                T = MFMA32(aA, bA, T);
                T = MFMA32(aB, bB, T);
                aA=aC; bA=bC; aB=aD; bB=bD;
            }
            T = MFMA32(aA, bA, T);
            T = MFMA32(aB, bB, T);
            T = MFMA32(aL, bL, T);
#undef UP
#undef HP
            // write tile to Tbuf in phase-2 A-fragment layout
            const int hl = 32*th + l31;
#pragma unroll
            for (int r = 0; r < 16; r += 2) {
                const int e_loc = 32*te + (r&3) + 8*(r>>2) + 4*kh;
                const int s_e = e_loc >> 3, e7 = e_loc & 7;
                unsigned lo = (unsigned short)f2bf(T[r]);
                unsigned hi = (unsigned short)f2bf(T[r+1]);
                *(unsigned*)(&Tbuf[((size_t)s_e*64 + hl)*8 + e7]) = lo | (hi << 16);
            }
        }
        __syncthreads();

        // ---- Phase 2: one 32x32 S-tile per wave, 26 K-steps ----
        ffrag S;
#pragma unroll
        for (int r = 0; r < 16; ++r) S[r] = 0.f;
        const short* tb = Tbuf + ((size_t)kh*64 + 32*ht + l31)*8;
        const short* cp = Cs + (csB + (size_t)kh*LL + c0)*8;
#define TB(es) (*(const bfrag*)(tb + (size_t)(es)*(2*64*8)))
#define CP(es) (*(const bfrag*)(cp + (size_t)(es)*(2*LL*8)))
        bfrag tA=TB(0), cA=CP(0), tB2=TB(1), cB=CP(1);
#pragma unroll 1
        for (int j = 0; j < 12; ++j) {
            bfrag tC=TB(2*j+2), cC=CP(2*j+2);
            bfrag tD=TB(2*j+3), cD=CP(2*j+3);
            S = MFMA32(tA,  cA, S);
            S = MFMA32(tB2, cB, S);
            tA=tC; cA=cC; tB2=tD; cB=cD;
        }
        S = MFMA32(tA,  cA, S);
        S = MFMA32(tB2, cB, S);
#undef TB
#undef CP

        // ---- per-k epilogue ----
        const float bk = bvec[k];
        const float* SDb = SD + ((size_t)b*KK + k)*LL;
        const float sev = SE[((size_t)b*KK + k)*LL + c0];
#pragma unroll
        for (int r = 0; r < 16; ++r) {
            const int hr = hbase + (r&3) + 8*(r>>2);
            const float ev = S[r] + SDb[hr] + sev + bk;
            if ((vb >> r) & 1) {
                E[r] += __expf(ev);
                if (c0 >= 1 && tag0 == k && head0 == hr) atomicAdd(&tgt[b], ev);
            }
        }
        __syncthreads();   // Tbuf overwritten by next k's phase 1
    }

    // ---- write this block's half-slice (exclusive, non-atomic) ----
    float* Ab = A8 + ((size_t)(g*BB + b))*LL*LL;
#pragma unroll
    for (int r = 0; r < 16; ++r) {
        const int hr = hbase + (r&3) + 8*(r>>2);
        Ab[hr*LL + c0] = E[r];
    }
}

// ---------------------------------------------------------------------------
// Register-resident LU logdet (unchanged).
// ---------------------------------------------------------------------------
__global__ __launch_bounds__(256) void k_logdet(
    const float* __restrict__ A8, const int* __restrict__ lengths,
    const float* __restrict__ tgt, float* __restrict__ out)
{
    const int b = blockIdx.x;
    const int t = threadIdx.x;
    const int rg = t >> 4;      // 0..15 row-group
    const int cg = t & 15;      // 0..15 col-group

    __shared__ float As[LL*LL];     // 64 KB
    __shared__ float Dg[128];       // col sums, then pivot stash
    __shared__ float Lbuf[128];
    __shared__ float Ubuf[128];
    __shared__ float red[256];

    const float4* A4 = (const float4*)A8;
    for (int f4 = t; f4 < 4096; f4 += 256) {
        float4 s = make_float4(0.f, 0.f, 0.f, 0.f);
#pragma unroll
        for (int g = 0; g < 8; ++g) {
            float4 v = A4[((size_t)(g*BB + b))*4096 + f4];
            s.x += v.x; s.y += v.y; s.z += v.z; s.w += v.w;
        }
        ((float4*)As)[f4] = s;
    }
    __syncthreads();

    if (t < 128) {
        float s = 0.f;
        for (int hr = 0; hr < LL; ++hr) s += As[hr*LL + t];
        Dg[t] = s * (1.0f + 1e-4f) + 1e-6f;
    }
    __syncthreads();

    const int n1 = lengths[b] - 1;
    float m[8][8];
#pragma unroll
    for (int r = 0; r < 8; ++r) {
        const int i = 8*rg + r;
#pragma unroll
        for (int c = 0; c < 8; ++c) {
            const int j = 8*cg + c;
            float v;
            if (i < n1 && j < n1)
                v = ((i == j) ? Dg[i+1] : 0.f) - As[(i+1)*LL + (j+1)];
            else
                v = (i == j) ? 1.f : 0.f;
            m[r][c] = v;
        }
    }
    __syncthreads();

    for (int j = 0; j < 127; ++j) {
        const int jg = j >> 3, jl = j & 7;
        if (cg == jg) {
#pragma unroll
            for (int c = 0; c < 8; ++c) {
                if (c == jl) {
#pragma unroll
                    for (int r = 0; r < 8; ++r) Lbuf[8*rg + r] = m[r][c];
                }
            }
        }
        if (rg == jg) {
#pragma unroll
            for (int r = 0; r < 8; ++r) {
                if (r == jl) {
#pragma unroll
                    for (int c = 0; c < 8; ++c) Ubuf[8*cg + c] = m[r][c];
                }
            }
        }
        __syncthreads();

        const float piv = Lbuf[j];
        if (t == j) Dg[j] = piv;
        const float rp = 1.0f / piv;
        float lr[8], ur[8];
#pragma unroll
        for (int r = 0; r < 8; ++r) lr[r] = Lbuf[8*rg + r] * rp;
#pragma unroll
        for (int c = 0; c < 8; ++c) ur[c] = Ubuf[8*cg + c];
#pragma unroll
        for (int r = 0; r < 8; ++r)
#pragma unroll
            for (int c = 0; c < 8; ++c)
                m[r][c] = fmaf(-lr[r], ur[c], m[r][c]);
        __syncthreads();
    }

    float lsum = 0.f;
    if (t < 127) lsum = logf(Dg[t]);
    red[t] = lsum;
    __syncthreads();
    for (int off = 128; off >= 1; off >>= 1) {
        if (t < off) red[t] += red[t + off];
        __syncthreads();
    }
    if (t == 0) out[b] = red[0] - tgt[b];
}

// ---------------------------------------------------------------------------
extern "C" void kernel_launch(void* const* d_in, const int* in_sizes, int n_in,
                              void* d_out, int out_size, void* d_ws, size_t ws_size,
                              hipStream_t stream) {
    const float* H    = (const float*)d_in[0];
    const float* C    = (const float*)d_in[1];
    const float* Wd   = (const float*)d_in[2];
    const float* We   = (const float*)d_in[3];
    const float* U    = (const float*)d_in[4];
    const float* bv   = (const float*)d_in[5];
    const float* mask = (const float*)d_in[6];
    const int* heads  = (const int*)d_in[7];
    const int* tags   = (const int*)d_in[8];
    const int* lens   = (const int*)d_in[9];
    float* out = (float*)d_out;

    // workspace layout
    char* p = (char*)d_ws;
    float* A8  = (float*)p;                 p += (size_t)8*BB*LL*LL*4;      // 16.78 MB
    float* tgt = (float*)p;                 p += 32*4;
    float* SDp = (float*)p;                 p += (size_t)BB*KK*LL*4;
    float* SEp = (float*)p;                 p += (size_t)BB*KK*LL*4;
    short* Hsp = (short*)p;                 p += (size_t)BB*SDN*LL*8*2;
    short* Csp = (short*)p;                 p += (size_t)BB*SEN*LL*8*2;
    short* Usp = (short*)p;                 p += (size_t)KK*SDN*EE*8*2;

    hipMemsetAsync(tgt, 0, 32*4, stream);

    p_hc  <<<dim3(1632), 256, 0, stream>>>(H, C, Hsp, Csp);
    p_u   <<<dim3(3250), 256, 0, stream>>>(U, Usp);
    k_sdse<<<dim3(BB, 4, 2), 256, 0, stream>>>(H, C, Wd, We, SDp, SEp);
    k_mfma<<<dim3(8, BB, 2), 512, 0, stream>>>(Hsp, Csp, Usp, SDp, SEp, bv, mask,
                                               heads, tags, A8, tgt);
    k_logdet<<<dim3(BB), 256, 0, stream>>>(A8, lens, tgt, out);
}